// Round 21
// baseline (425.931 us; speedup 1.0000x reference)
//
#include <hip/hip_runtime.h>
#include <hip/hip_bf16.h>

#define NN 50000
#define EE 800000

// mega1 block layout: 782 groups of {2 gemm, 1 rank(2048 edges)} = 2346,
// then 3125 cvt-x blocks (1024 float4 each), then 64 wcat blocks (1024 each).
#define MG_INTER 2346
#define MG_CVX0  2346
#define MG_CVXN  3125
#define MG_WC0   5471
#define MG_GRID  5535

// place_cvt: 6250 place blocks + 12500 bf16->fp8 cvt blocks
#define PLC_PLACE 6250
#define PLC_GRID  18750

#define LOG2E 1.4426950408889634f

typedef __attribute__((ext_vector_type(8))) short short8v;
typedef __attribute__((ext_vector_type(4))) float f32x4;
typedef __attribute__((ext_vector_type(2))) float f32x2;

__device__ __forceinline__ float bf2f(unsigned short u) {
    return __uint_as_float(((unsigned int)u) << 16);
}
__device__ __forceinline__ float bflo(unsigned int u) {
    return __uint_as_float(u << 16);
}
__device__ __forceinline__ float bfhi(unsigned int u) {
    return __uint_as_float(u & 0xffff0000u);
}
__device__ __forceinline__ unsigned short f2bf(float f) {
    unsigned int u = __float_as_uint(f);
    unsigned int r = 0x7FFF + ((u >> 16) & 1);
    return (unsigned short)((u + r) >> 16);
}
__device__ __forceinline__ unsigned cvtpk(float lo, float hi) {
    unsigned r;
    asm("v_cvt_pk_bf16_f32 %0, %1, %2" : "=v"(r) : "v"(lo), "v"(hi));
    return r;
}
__device__ __forceinline__ float exp2a(float x) {      // 2^x, single v_exp_f32
    float r;
    asm("v_exp_f32 %0, %1" : "=v"(r) : "v"(x));
    return r;
}
__device__ __forceinline__ f32x2 abs2(f32x2 v) {
    return __builtin_elementwise_abs(v);
}

// DPP butterfly add within a 16-lane row (pure VALU, no LDS pipe).
template<int CTRL>
__device__ __forceinline__ float dppadd(float v) {
    int iv = __float_as_int(v);
    int p = __builtin_amdgcn_update_dpp(0, iv, CTRL, 0xF, 0xF, true);
    return v + __int_as_float(p);
}
#define ROW16_REDUCE(w) \
    w = dppadd<0xB1>(w);  /* quad_perm [1,0,3,2]  : xor1 */ \
    w = dppadd<0x4E>(w);  /* quad_perm [2,3,0,1]  : xor2 */ \
    w = dppadd<0x141>(w); /* ROW_HALF_MIRROR      : quads -> 8 */ \
    w = dppadd<0x140>(w); /* ROW_MIRROR           : 8s -> 16 */

// ---------------- CSR: scan of counts -> rowptr ----------------
__global__ __launch_bounds__(1024) void scan_k(const int* __restrict__ cursor, int* __restrict__ rowptr) {
    int r = blockIdx.x;
    const int* cnt = cursor + (size_t)r * NN;
    int* rp  = rowptr + r * (NN + 1);
    int tid = threadIdx.x;
    const int CH = (NN + 1023) / 1024;   // 49
    int beg = tid * CH;
    int end = beg + CH; if (end > NN) end = NN;
    int s = 0;
    for (int i = beg; i < end && i < NN; ++i) s += cnt[i];
    __shared__ int sums[1024];
    sums[tid] = s;
    __syncthreads();
    for (int offd = 1; offd < 1024; offd <<= 1) {
        int v = 0;
        if (tid >= offd) v = sums[tid - offd];
        __syncthreads();
        sums[tid] += v;
        __syncthreads();
    }
    int run = sums[tid] - s;
    for (int i = beg; i < end && i < NN; ++i) {
        int c = cnt[i];
        rp[i] = run;
        run += c;
    }
    if (tid == 1023) rp[NN] = sums[1023];
}

// place (no atomics) + feat1 bf16 -> fp8 e4m3 conversion, co-scheduled
__global__ void place_cvt_k(const int* __restrict__ src, const int* __restrict__ dst,
                            const int* __restrict__ rank, const int* __restrict__ rowptr,
                            int* __restrict__ csr,
                            const unsigned short* __restrict__ feat1,  // [2][NN][256] bf16
                            unsigned char* __restrict__ feat8)         // [2][NN][256] fp8
{
    int bid = blockIdx.x;
    if (bid < PLC_PLACE) {
        int i = bid * 256 + threadIdx.x;
        if (i >= 2 * EE) return;
        int r = (i >= EE) ? 1 : 0;
        int d = dst[i];
        int pos = rowptr[r * (NN + 1) + d] + rank[i];
        csr[r * EE + pos] = src[i];
        return;
    }
    // cvt: 8 bf16 -> 8 fp8 per thread
    int i = (bid - PLC_PLACE) * 256 + threadIdx.x;   // < 3,200,000 exactly
    uint4 v = reinterpret_cast<const uint4*>(feat1)[i];
    int w0 = __builtin_amdgcn_cvt_pk_fp8_f32(bflo(v.x), bfhi(v.x), 0, false);
    w0 = __builtin_amdgcn_cvt_pk_fp8_f32(bflo(v.y), bfhi(v.y), w0, true);
    int w1 = __builtin_amdgcn_cvt_pk_fp8_f32(bflo(v.z), bfhi(v.z), 0, false);
    w1 = __builtin_amdgcn_cvt_pk_fp8_f32(bflo(v.w), bfhi(v.w), w1, true);
    uint2 o; o.x = (unsigned)w0; o.y = (unsigned)w1;
    reinterpret_cast<uint2*>(feat8)[i] = o;
}

// ---------------- mega1: L1 GEMM (fp32 in, inline cvt) + rank + cvt-x + wcat ----------------
__global__ __launch_bounds__(256) void mega1_k(
    const float* __restrict__ X,       // [NN][256] fp32
    const float* __restrict__ W1,      // [2][256][256] fp32
    unsigned short* __restrict__ Cout, // [2][NN][256] bf16
    const int* __restrict__ dst, int* __restrict__ cursor, int* __restrict__ rank,
    unsigned short* __restrict__ xb,   // [NN][256] bf16 out
    const float* __restrict__ W2, const float* __restrict__ Wres2,
    unsigned short* __restrict__ Wcatb)
{
    __shared__ unsigned short sA[128][72];
    __shared__ unsigned short sB[128][72];
    int bid = blockIdx.x;
    int tid = threadIdx.x;

    if (bid >= MG_INTER) {
        if (bid < MG_WC0) {
            // cvt x -> xb: 4 float4 per thread
            int base = (bid - MG_CVX0) * 1024 + tid;     // 3125*1024 = 3,200,000 exactly
            #pragma unroll
            for (int k = 0; k < 4; ++k) {
                int i = base + k * 256;
                float4 v = reinterpret_cast<const float4*>(X)[i];
                uint2 o;
                o.x = cvtpk(v.x, v.y);
                o.y = cvtpk(v.z, v.w);
                reinterpret_cast<uint2*>(xb)[i] = o;
            }
        } else {
            // build Wcat bf16: 4 per thread
            int base = (bid - MG_WC0) * 1024 + tid;      // 64*1024 = 65536 exactly
            #pragma unroll
            for (int k = 0; k < 4; ++k) {
                int i = base + k * 256;
                int o = i >> 8, kk = i & 255;
                int sel = o >> 6, row = o & 63, r = sel >> 1;
                const float* Wsrc = (sel & 1) ? Wres2 : W2;
                Wcatb[i] = f2bf(Wsrc[((size_t)r * 64 + row) * 256 + kk]);
            }
        }
        return;
    }

    int grp = bid / 3, m = bid % 3;
    if (m == 2) {
        // rank block: 2048 edges, 8 pipelined atomics per thread
        int base = grp * 2048 + tid;
        #pragma unroll
        for (int k = 0; k < 8; ++k) {
            int i = base + k * 256;
            if (i < 2 * EE) {
                int r = (i >= EE) ? 1 : 0;
                rank[i] = atomicAdd(&cursor[(size_t)r * NN + dst[i]], 1);
            }
        }
        return;
    }

    // gemm block g : 128x128 tile, K=256
    int g = grp * 2 + m;                 // 0..1563
    const int K = 256;
    int bx = g % 391, by = (g / 391) & 1, bz = g / 782;
    int wid = tid >> 6, lane = tid & 63;
    int wr = wid >> 1, wc = wid & 1;
    int n0 = bx * 128;
    int o0 = by * 128;
    const float* Wr = W1 + (size_t)bz * 256 * 256;

    f32x4 acc[4][4] = {};

    for (int k0 = 0; k0 < K; k0 += 64) {
        #pragma unroll
        for (int p = 0; p < 4; ++p) {
            int flat = p * 256 + tid;
            int row = flat >> 3, k8 = (flat & 7) * 8;
            int gr = n0 + row;
            float4 xa = {0.f, 0.f, 0.f, 0.f}, xc = {0.f, 0.f, 0.f, 0.f};
            if (gr < NN) {
                const float* xp = X + (size_t)gr * K + k0 + k8;
                xa = *reinterpret_cast<const float4*>(xp);
                xc = *reinterpret_cast<const float4*>(xp + 4);
            }
            uint4 pa;
            pa.x = cvtpk(xa.x, xa.y); pa.y = cvtpk(xa.z, xa.w);
            pa.z = cvtpk(xc.x, xc.y); pa.w = cvtpk(xc.z, xc.w);
            *reinterpret_cast<uint4*>(&sA[row][k8]) = pa;
            const float* wp = Wr + (size_t)(o0 + row) * K + k0 + k8;
            float4 wa = *reinterpret_cast<const float4*>(wp);
            float4 wb = *reinterpret_cast<const float4*>(wp + 4);
            uint4 pb;
            pb.x = cvtpk(wa.x, wa.y); pb.y = cvtpk(wa.z, wa.w);
            pb.z = cvtpk(wb.x, wb.y); pb.w = cvtpk(wb.z, wb.w);
            *reinterpret_cast<uint4*>(&sB[row][k8]) = pb;
        }
        __syncthreads();
        #pragma unroll
        for (int kk = 0; kk < 2; ++kk) {
            short8v af[4], bf[4];
            int klo = kk * 32 + (lane >> 4) * 8;
            #pragma unroll
            for (int mm = 0; mm < 4; ++mm)
                af[mm] = *reinterpret_cast<const short8v*>(&sA[wr * 64 + mm * 16 + (lane & 15)][klo]);
            #pragma unroll
            for (int nn = 0; nn < 4; ++nn)
                bf[nn] = *reinterpret_cast<const short8v*>(&sB[wc * 64 + nn * 16 + (lane & 15)][klo]);
            #pragma unroll
            for (int mm = 0; mm < 4; ++mm)
                #pragma unroll
                for (int nn = 0; nn < 4; ++nn)
                    acc[mm][nn] = __builtin_amdgcn_mfma_f32_16x16x32_bf16(af[mm], bf[nn], acc[mm][nn], 0, 0, 0);
        }
        __syncthreads();
    }
    int col0 = o0 + wc * 64;
    int rbase = (lane >> 4) * 4;
    #pragma unroll
    for (int mm = 0; mm < 4; ++mm) {
        #pragma unroll
        for (int j = 0; j < 4; ++j) {
            int gr = n0 + wr * 64 + mm * 16 + rbase + j;
            if (gr >= NN) continue;
            #pragma unroll
            for (int nn = 0; nn < 4; ++nn) {
                int gc = col0 + nn * 16 + (lane & 15);
                size_t idx = (size_t)bz * NN * 256 + (size_t)gr * 256 + gc;
                Cout[idx] = f2bf(acc[mm][nn][j]);
            }
        }
    }
}

// ---------------- Layer-2 GEMM with fused post2 epilogue (feat2 bf16) ----------------
__global__ __launch_bounds__(256) void gemm2_k(
    const unsigned short* __restrict__ A,   // [NN][256] bf16 (hb)
    const unsigned short* __restrict__ W,   // [256][256] bf16 (Wcat)
    unsigned short* __restrict__ feat2,     // [2][NN][64] bf16
    float* __restrict__ base0, float* __restrict__ base1)
{
    __shared__ unsigned short sA[128][72];
    __shared__ unsigned short sB[128][72];
    const int K = 256;
    int tid = threadIdx.x;
    int wid = tid >> 6, lane = tid & 63;
    int wr = wid >> 1, wc = wid & 1;
    int n0 = blockIdx.x * 128;
    int o0 = blockIdx.y * 128;

    f32x4 acc[4][4] = {};

    for (int k0 = 0; k0 < K; k0 += 64) {
        #pragma unroll
        for (int p = 0; p < 4; ++p) {
            int flat = p * 256 + tid;
            int row = flat >> 3, k8 = (flat & 7) * 8;
            int gr = n0 + row;
            short8v va = {0, 0, 0, 0, 0, 0, 0, 0};
            if (gr < NN) va = *reinterpret_cast<const short8v*>(A + (size_t)gr * K + k0 + k8);
            *reinterpret_cast<short8v*>(&sA[row][k8]) = va;
            short8v vb = *reinterpret_cast<const short8v*>(W + (size_t)(o0 + row) * K + k0 + k8);
            *reinterpret_cast<short8v*>(&sB[row][k8]) = vb;
        }
        __syncthreads();
        #pragma unroll
        for (int kk = 0; kk < 2; ++kk) {
            short8v af[4], bf[4];
            int klo = kk * 32 + (lane >> 4) * 8;
            #pragma unroll
            for (int m = 0; m < 4; ++m)
                af[m] = *reinterpret_cast<const short8v*>(&sA[wr * 64 + m * 16 + (lane & 15)][klo]);
            #pragma unroll
            for (int n = 0; n < 4; ++n)
                bf[n] = *reinterpret_cast<const short8v*>(&sB[wc * 64 + n * 16 + (lane & 15)][klo]);
            #pragma unroll
            for (int m = 0; m < 4; ++m)
                #pragma unroll
                for (int n = 0; n < 4; ++n)
                    acc[m][n] = __builtin_amdgcn_mfma_f32_16x16x32_bf16(af[m], bf[n], acc[m][n], 0, 0, 0);
        }
        __syncthreads();
    }
    int col0 = o0 + wc * 64;
    int sel = col0 >> 6;            // wave-uniform: 0..3
    int rbase = (lane >> 4) * 4;
    #pragma unroll
    for (int m = 0; m < 4; ++m) {
        #pragma unroll
        for (int j = 0; j < 4; ++j) {
            int gr = n0 + wr * 64 + m * 16 + rbase + j;
            if (gr >= NN) continue;
            #pragma unroll
            for (int n = 0; n < 4; ++n) {
                int d = n * 16 + (lane & 15);
                float v = acc[m][n][j];
                size_t o = (size_t)gr * 64 + d;
                if (sel == 0)      feat2[o] = f2bf(v);
                else if (sel == 1) base0[o] = v;
                else if (sel == 2) feat2[(size_t)NN * 64 + o] = f2bf(v);
                else               base1[o] = v;
            }
        }
    }
}

// ---------------- Layer-1 edge softmax + aggregation (H=4, D=64) ----------------
// 2 independent waves per 128-thread WG (2 nodes/WG): occupancy 24->32 waves/CU,
// retirement tail only ~1.10 (R3's 4-wave tail was 1.47 - matched E[max] model).
__global__ __launch_bounds__(128) void agg1_k(
    const unsigned char* __restrict__ feat8,   // [2][NN][256] fp8 e4m3
    const unsigned short* __restrict__ xb,     // [NN][256] bf16 (residual)
    const float* __restrict__ a1,              // [2][256]
    const float* __restrict__ b1,              // [2][256]
    const int* __restrict__ rowptr, const int* __restrict__ csr,
    unsigned short* __restrict__ hb)           // [NN][256] bf16 out
{
    int lane = threadIdx.x & 63;
    int n = (blockIdx.x << 1) | (threadIdx.x >> 6);
    if (n >= NN) return;
    unsigned laneoff = (unsigned)lane * 4u;    // 4 bytes per lane in a 256B row
    int c = lane * 4;
    float4 av0v = *reinterpret_cast<const float4*>(a1 + c);
    float4 av1v = *reinterpret_cast<const float4*>(a1 + 256 + c);
    f32x2 P01[2], P23[2], Q01[2], Q23[2];     // pre-scaled by log2(e)
    P01[0] = f32x2{0.6f * LOG2E * av0v.x, 0.6f * LOG2E * av0v.y};
    P23[0] = f32x2{0.6f * LOG2E * av0v.z, 0.6f * LOG2E * av0v.w};
    Q01[0] = f32x2{0.4f * LOG2E * av0v.x, 0.4f * LOG2E * av0v.y};
    Q23[0] = f32x2{0.4f * LOG2E * av0v.z, 0.4f * LOG2E * av0v.w};
    P01[1] = f32x2{0.6f * LOG2E * av1v.x, 0.6f * LOG2E * av1v.y};
    P23[1] = f32x2{0.6f * LOG2E * av1v.z, 0.6f * LOG2E * av1v.w};
    Q01[1] = f32x2{0.4f * LOG2E * av1v.x, 0.4f * LOG2E * av1v.y};
    Q23[1] = f32x2{0.4f * LOG2E * av1v.z, 0.4f * LOG2E * av1v.w};
    float bsum0 = b1[c + 0] + b1[256 + c + 0];
    float bsum1 = b1[c + 1] + b1[256 + c + 1];
    float bsum2 = b1[c + 2] + b1[256 + c + 2];
    float bsum3 = b1[c + 3] + b1[256 + c + 3];

    f32x2 t01 = {0.f, 0.f}, t23 = {0.f, 0.f};
    #pragma unroll
    for (int r = 0; r < 2; ++r) {
        const char* frB = (const char*)(feat8 + (size_t)r * NN * 256);
        unsigned ud = *reinterpret_cast<const unsigned*>(frB + (((unsigned)n << 8) | laneoff));
        f32x2 fd01 = __builtin_amdgcn_cvt_pk_f32_fp8(ud, false);
        f32x2 fd23 = __builtin_amdgcn_cvt_pk_f32_fp8(ud, true);
        f32x2 Pa = P01[r], Pb = P23[r], Qa = Q01[r], Qb = Q23[r];
        float lsum = 0.f;
        f32x2 a01 = {0.f, 0.f}, a23 = {0.f, 0.f};
        int beg = rowptr[r * (NN + 1) + n], end = rowptr[r * (NN + 1) + n + 1];
        const int* cp = csr + (size_t)r * EE;
        int e = beg;
        for (; e + 2 <= end; e += 2) {
            int s0 = cp[e], s1 = cp[e + 1];
            unsigned u0 = *reinterpret_cast<const unsigned*>(frB + (((unsigned)s0 << 8) | laneoff));
            unsigned u1 = *reinterpret_cast<const unsigned*>(frB + (((unsigned)s1 << 8) | laneoff));
            f32x2 f0a = __builtin_amdgcn_cvt_pk_f32_fp8(u0, false);
            f32x2 f0b = __builtin_amdgcn_cvt_pk_f32_fp8(u0, true);
            f32x2 f1a = __builtin_amdgcn_cvt_pk_f32_fp8(u1, false);
            f32x2 f1b = __builtin_amdgcn_cvt_pk_f32_fp8(u1, true);
            f32x2 t, wv0, wv1;
            t = f0a + fd01; wv0  = Pa * t + Qa * abs2(t);
            t = f0b + fd23; wv0 += Pb * t; wv0 += Qb * abs2(t);
            t = f1a + fd01; wv1  = Pa * t + Qa * abs2(t);
            t = f1b + fd23; wv1 += Pb * t; wv1 += Qb * abs2(t);
            float w0 = wv0.x + wv0.y, w1 = wv1.x + wv1.y;
            ROW16_REDUCE(w0)
            ROW16_REDUCE(w1)
            float p0 = exp2a(w0), p1 = exp2a(w1);
            lsum += p0 + p1;
            f32x2 pb0 = f32x2{p0, p0}, pb1 = f32x2{p1, p1};
            a01 += pb0 * f0a; a23 += pb0 * f0b;
            a01 += pb1 * f1a; a23 += pb1 * f1b;
        }
        if (e < end) {
            int s = cp[e];
            unsigned us = *reinterpret_cast<const unsigned*>(frB + (((unsigned)s << 8) | laneoff));
            f32x2 fa = __builtin_amdgcn_cvt_pk_f32_fp8(us, false);
            f32x2 fb = __builtin_amdgcn_cvt_pk_f32_fp8(us, true);
            f32x2 t, wv;
            t = fa + fd01; wv  = Pa * t + Qa * abs2(t);
            t = fb + fd23; wv += Pb * t; wv += Qb * abs2(t);
            float w = wv.x + wv.y;
            ROW16_REDUCE(w)
            float p = exp2a(w);
            lsum += p;
            f32x2 pbv = f32x2{p, p};
            a01 += pbv * fa; a23 += pbv * fb;
        }
        float inv = 1.f / fmaxf(lsum, 1e-16f);
        f32x2 iv = f32x2{inv, inv};
        t01 += a01 * iv; t23 += a23 * iv;
    }
    unsigned o = ((unsigned)n << 8) + (unsigned)c;
    uint2 xv = *reinterpret_cast<const uint2*>(xb + o);
    float v0 = fmaxf(t01.x + 2.f * bflo(xv.x) + bsum0, 0.f);
    float v1 = fmaxf(t01.y + 2.f * bfhi(xv.x) + bsum1, 0.f);
    float v2 = fmaxf(t23.x + 2.f * bflo(xv.y) + bsum2, 0.f);
    float v3 = fmaxf(t23.y + 2.f * bfhi(xv.y) + bsum3, 0.f);
    ushort4 ho;
    ho.x = f2bf(v0); ho.y = f2bf(v1); ho.z = f2bf(v2); ho.w = f2bf(v3);
    reinterpret_cast<ushort4*>(hb)[((unsigned)n << 6) + (unsigned)lane] = ho;
}

// ---------------- Layer-2 edge softmax + aggregation (H=1, D=64), 4-edge ILP, 2 nodes/WG ----------------
__global__ __launch_bounds__(128) void agg2_k(
    const unsigned short* __restrict__ feat2,  // [2][NN][64] bf16
    const float* __restrict__ base0, const float* __restrict__ base1,
    const float* __restrict__ a2,              // [2][64]
    const float* __restrict__ b2,              // [2][64]
    const int* __restrict__ rowptr, const int* __restrict__ csr,
    float* __restrict__ out)
{
    int lane = threadIdx.x & 63;
    int n = (blockIdx.x << 1) | (threadIdx.x >> 6);
    if (n >= NN) return;
    unsigned laneoff = (unsigned)lane * 2u;
    float av0 = a2[lane], av1 = a2[64 + lane];
    float p6a[2] = {0.6f * LOG2E * av0, 0.6f * LOG2E * av1};
    float q4a[2] = {0.4f * LOG2E * av0, 0.4f * LOG2E * av1};
    float bs = b2[lane] + b2[64 + lane];

    float tot = 0.f;
    #pragma unroll
    for (int r = 0; r < 2; ++r) {
        const char* frB = (const char*)(feat2 + (size_t)r * NN * 64);
        float fd = bf2f(*reinterpret_cast<const unsigned short*>(frB + (((unsigned)n << 7) | laneoff)));
        float P = p6a[r], Q = q4a[r];
        float lsum = 0.f, acc = 0.f;
        int beg = rowptr[r * (NN + 1) + n], end = rowptr[r * (NN + 1) + n + 1];
        const int* cp = csr + (size_t)r * EE;
        int e = beg;
        for (; e + 4 <= end; e += 4) {
            int s0 = cp[e], s1 = cp[e + 1], s2 = cp[e + 2], s3 = cp[e + 3];
            float fs0 = bf2f(*reinterpret_cast<const unsigned short*>(frB + (((unsigned)s0 << 7) | laneoff)));
            float fs1 = bf2f(*reinterpret_cast<const unsigned short*>(frB + (((unsigned)s1 << 7) | laneoff)));
            float fs2 = bf2f(*reinterpret_cast<const unsigned short*>(frB + (((unsigned)s2 << 7) | laneoff)));
            float fs3 = bf2f(*reinterpret_cast<const unsigned short*>(frB + (((unsigned)s3 << 7) | laneoff)));
            float ta = fs0 + fd, tb = fs1 + fd, tc = fs2 + fd, td = fs3 + fd;
            float P0 = P * ta + Q * fabsf(ta);
            float P1 = P * tb + Q * fabsf(tb);
            float P2 = P * tc + Q * fabsf(tc);
            float P3 = P * td + Q * fabsf(td);
            ROW16_REDUCE(P0) ROW16_REDUCE(P1) ROW16_REDUCE(P2) ROW16_REDUCE(P3)
            P0 += __shfl_xor(P0, 16); P1 += __shfl_xor(P1, 16); P2 += __shfl_xor(P2, 16); P3 += __shfl_xor(P3, 16);
            P0 += __shfl_xor(P0, 32); P1 += __shfl_xor(P1, 32); P2 += __shfl_xor(P2, 32); P3 += __shfl_xor(P3, 32);
            float p0 = exp2a(P0), p1 = exp2a(P1), p2 = exp2a(P2), p3 = exp2a(P3);
            lsum += (p0 + p1) + (p2 + p3);
            acc += p0 * fs0; acc += p1 * fs1; acc += p2 * fs2; acc += p3 * fs3;
        }
        for (; e < end; ++e) {
            int s = cp[e];
            float fs = bf2f(*reinterpret_cast<const unsigned short*>(frB + (((unsigned)s << 7) | laneoff)));
            float t = fs + fd;
            float w = P * t + Q * fabsf(t);
            ROW16_REDUCE(w)
            w += __shfl_xor(w, 16);
            w += __shfl_xor(w, 32);
            float p = exp2a(w);
            lsum += p;
            acc += p * fs;
        }
        tot += acc / fmaxf(lsum, 1e-16f);
    }
    unsigned o = ((unsigned)n << 6) + (unsigned)lane;
    out[o] = fmaxf(tot + base0[o] + base1[o] + bs, 0.f);
}

extern "C" void kernel_launch(void* const* d_in, const int* in_sizes, int n_in,
                              void* d_out, int out_size, void* d_ws, size_t ws_size,
                              hipStream_t stream) {
    (void)in_sizes; (void)n_in; (void)out_size; (void)ws_size;
    const float* x     = (const float*)d_in[0];
    const int*   src   = (const int*)d_in[1];
    const int*   dst   = (const int*)d_in[2];
    const float* W1    = (const float*)d_in[3];
    const float* a1    = (const float*)d_in[4];
    const float* b1    = (const float*)d_in[5];
    const float* W2    = (const float*)d_in[6];
    const float* a2    = (const float*)d_in[7];
    const float* b2    = (const float*)d_in[8];
    const float* Wres2 = (const float*)d_in[9];
    float* out = (float*)d_out;

    char* w = (char*)d_ws;
    size_t off = 0;
    auto alloc = [&](size_t bytes) -> void* {
        void* p = w + off;
        off = (off + bytes + 255) & ~(size_t)255;
        return p;
    };
    int* cursor = (int*)alloc((size_t)2 * NN * sizeof(int));
    int* rowptr = (int*)alloc((size_t)2 * (NN + 1) * sizeof(int));
    int* csr    = (int*)alloc((size_t)2 * EE * sizeof(int));
    int* rankb  = (int*)alloc((size_t)2 * EE * sizeof(int));
    unsigned short* feat1 = (unsigned short*)alloc((size_t)2 * NN * 256 * 2);
    unsigned short* xb = (unsigned short*)alloc((size_t)NN * 256 * 2);
    unsigned short* hb = (unsigned short*)alloc((size_t)NN * 256 * 2);
    unsigned short* Wcatb = (unsigned short*)alloc((size_t)256 * 256 * 2);
    unsigned short* feat2 = (unsigned short*)alloc((size_t)2 * NN * 64 * 2);
    // feat8 (25.6 MB) aliases base0/base1: feat8 dead after agg1; gemm2 then
    // writes base0/base1 over it; agg2 reads base. Sequentially safe each call.
    unsigned char* feat8 = (unsigned char*)alloc((size_t)2 * NN * 256);
    float* base0 = (float*)feat8;
    float* base1 = base0 + (size_t)NN * 64;

    hipMemsetAsync(cursor, 0, (size_t)2 * NN * sizeof(int), stream);

    // mega1: L1 GEMM + rank atomics + cvt-x + wcat, co-scheduled
    mega1_k<<<MG_GRID, 256, 0, stream>>>(x, W1, feat1, dst, cursor, rankb, xb, W2, Wres2, Wcatb);
    scan_k<<<2, 1024, 0, stream>>>(cursor, rowptr);
    place_cvt_k<<<PLC_GRID, 256, 0, stream>>>(src, dst, rankb, rowptr, csr, feat1, feat8);

    agg1_k<<<(NN + 1) / 2, 128, 0, stream>>>(feat8, xb, a1, b1, rowptr, csr, hb);

    // Layer 2: GEMM with fused post2 epilogue (bf16 feat2)
    dim3 g2(391, 2, 1);
    gemm2_k<<<g2, 256, 0, stream>>>(hb, Wcatb, feat2, base0, base1);
    agg2_k<<<(NN + 1) / 2, 128, 0, stream>>>(feat2, base0, base1, a2, b2, rowptr, csr, out);
}

// Round 22
// 371.164 us; speedup vs baseline: 1.1476x; 1.1476x over previous
//
#include <hip/hip_runtime.h>
#include <hip/hip_bf16.h>

#define NN 50000
#define EE 800000

// mega1 block layout: 782 groups of {2 gemm, 1 rank(2048 edges)} = 2346,
// then 3125 cvt-x blocks (1024 float4 each), then 64 wcat blocks (1024 each).
#define MG_INTER 2346
#define MG_CVX0  2346
#define MG_WC0   5471
#define MG_GRID  5535

#define LOG2E 1.4426950408889634f

typedef __attribute__((ext_vector_type(8))) short short8v;
typedef __attribute__((ext_vector_type(4))) float f32x4;
typedef __attribute__((ext_vector_type(2))) float f32x2;

__device__ __forceinline__ float bf2f(unsigned short u) {
    return __uint_as_float(((unsigned int)u) << 16);
}
__device__ __forceinline__ float bflo(unsigned int u) {
    return __uint_as_float(u << 16);
}
__device__ __forceinline__ float bfhi(unsigned int u) {
    return __uint_as_float(u & 0xffff0000u);
}
__device__ __forceinline__ unsigned short f2bf(float f) {
    unsigned int u = __float_as_uint(f);
    unsigned int r = 0x7FFF + ((u >> 16) & 1);
    return (unsigned short)((u + r) >> 16);
}
__device__ __forceinline__ unsigned cvtpk(float lo, float hi) {
    unsigned r;
    asm("v_cvt_pk_bf16_f32 %0, %1, %2" : "=v"(r) : "v"(lo), "v"(hi));
    return r;
}
__device__ __forceinline__ unsigned char f2fp8(float v) {
    int r = __builtin_amdgcn_cvt_pk_fp8_f32(v, v, 0, false);
    return (unsigned char)(r & 0xFF);
}
__device__ __forceinline__ float exp2a(float x) {      // 2^x, single v_exp_f32
    float r;
    asm("v_exp_f32 %0, %1" : "=v"(r) : "v"(x));
    return r;
}
__device__ __forceinline__ f32x2 abs2(f32x2 v) {
    return __builtin_elementwise_abs(v);
}

// DPP butterfly add within a 16-lane row (pure VALU, no LDS pipe).
template<int CTRL>
__device__ __forceinline__ float dppadd(float v) {
    int iv = __float_as_int(v);
    int p = __builtin_amdgcn_update_dpp(0, iv, CTRL, 0xF, 0xF, true);
    return v + __int_as_float(p);
}
#define ROW16_REDUCE(w) \
    w = dppadd<0xB1>(w);  /* quad_perm [1,0,3,2]  : xor1 */ \
    w = dppadd<0x4E>(w);  /* quad_perm [2,3,0,1]  : xor2 */ \
    w = dppadd<0x141>(w); /* ROW_HALF_MIRROR      : quads -> 8 */ \
    w = dppadd<0x140>(w); /* ROW_MIRROR           : 8s -> 16 */

// ---------------- CSR: scan of counts -> rowptr ----------------
__global__ __launch_bounds__(1024) void scan_k(const int* __restrict__ cursor, int* __restrict__ rowptr) {
    int r = blockIdx.x;
    const int* cnt = cursor + (size_t)r * NN;
    int* rp  = rowptr + r * (NN + 1);
    int tid = threadIdx.x;
    const int CH = (NN + 1023) / 1024;   // 49
    int beg = tid * CH;
    int end = beg + CH; if (end > NN) end = NN;
    int s = 0;
    for (int i = beg; i < end && i < NN; ++i) s += cnt[i];
    __shared__ int sums[1024];
    sums[tid] = s;
    __syncthreads();
    for (int offd = 1; offd < 1024; offd <<= 1) {
        int v = 0;
        if (tid >= offd) v = sums[tid - offd];
        __syncthreads();
        sums[tid] += v;
        __syncthreads();
    }
    int run = sums[tid] - s;
    for (int i = beg; i < end && i < NN; ++i) {
        int c = cnt[i];
        rp[i] = run;
        run += c;
    }
    if (tid == 1023) rp[NN] = sums[1023];
}

// place: no atomics — csr[rowptr[dst]+rank] = src
__global__ void place_k(const int* __restrict__ src, const int* __restrict__ dst,
                        const int* __restrict__ rank, const int* __restrict__ rowptr,
                        int* __restrict__ csr) {
    int i = blockIdx.x * 256 + threadIdx.x;
    if (i >= 2 * EE) return;
    int r = (i >= EE) ? 1 : 0;
    int d = dst[i];
    int pos = rowptr[r * (NN + 1) + d] + rank[i];
    csr[r * EE + pos] = src[i];
}

// ---------------- mega1: L1 GEMM (fp32 in, fp8 out direct) + rank + cvt-x + wcat ----------------
__global__ __launch_bounds__(256) void mega1_k(
    const float* __restrict__ X,       // [NN][256] fp32
    const float* __restrict__ W1,      // [2][256][256] fp32
    unsigned char* __restrict__ feat8, // [2][NN][256] fp8 e4m3 (direct epilogue)
    const int* __restrict__ dst, int* __restrict__ cursor, int* __restrict__ rank,
    unsigned short* __restrict__ xb,   // [NN][256] bf16 out
    const float* __restrict__ W2, const float* __restrict__ Wres2,
    unsigned short* __restrict__ Wcatb)
{
    __shared__ unsigned short sA[128][72];
    __shared__ unsigned short sB[128][72];
    int bid = blockIdx.x;
    int tid = threadIdx.x;

    if (bid >= MG_INTER) {
        if (bid < MG_WC0) {
            // cvt x -> xb: 4 float4 per thread
            int base = (bid - MG_CVX0) * 1024 + tid;     // 3125*1024 = 3,200,000 exactly
            #pragma unroll
            for (int k = 0; k < 4; ++k) {
                int i = base + k * 256;
                float4 v = reinterpret_cast<const float4*>(X)[i];
                uint2 o;
                o.x = cvtpk(v.x, v.y);
                o.y = cvtpk(v.z, v.w);
                reinterpret_cast<uint2*>(xb)[i] = o;
            }
        } else {
            // build Wcat bf16: 4 per thread
            int base = (bid - MG_WC0) * 1024 + tid;      // 64*1024 = 65536 exactly
            #pragma unroll
            for (int k = 0; k < 4; ++k) {
                int i = base + k * 256;
                int o = i >> 8, kk = i & 255;
                int sel = o >> 6, row = o & 63, r = sel >> 1;
                const float* Wsrc = (sel & 1) ? Wres2 : W2;
                Wcatb[i] = f2bf(Wsrc[((size_t)r * 64 + row) * 256 + kk]);
            }
        }
        return;
    }

    int grp = bid / 3, m = bid % 3;
    if (m == 2) {
        // rank block: 2048 edges, 8 pipelined atomics per thread
        int base = grp * 2048 + tid;
        #pragma unroll
        for (int k = 0; k < 8; ++k) {
            int i = base + k * 256;
            if (i < 2 * EE) {
                int r = (i >= EE) ? 1 : 0;
                rank[i] = atomicAdd(&cursor[(size_t)r * NN + dst[i]], 1);
            }
        }
        return;
    }

    // gemm block g : 128x128 tile, K=256
    int g = grp * 2 + m;                 // 0..1563
    const int K = 256;
    int bx = g % 391, by = (g / 391) & 1, bz = g / 782;
    int wid = tid >> 6, lane = tid & 63;
    int wr = wid >> 1, wc = wid & 1;
    int n0 = bx * 128;
    int o0 = by * 128;
    const float* Wr = W1 + (size_t)bz * 256 * 256;

    f32x4 acc[4][4] = {};

    for (int k0 = 0; k0 < K; k0 += 64) {
        #pragma unroll
        for (int p = 0; p < 4; ++p) {
            int flat = p * 256 + tid;
            int row = flat >> 3, k8 = (flat & 7) * 8;
            int gr = n0 + row;
            float4 xa = {0.f, 0.f, 0.f, 0.f}, xc = {0.f, 0.f, 0.f, 0.f};
            if (gr < NN) {
                const float* xp = X + (size_t)gr * K + k0 + k8;
                xa = *reinterpret_cast<const float4*>(xp);
                xc = *reinterpret_cast<const float4*>(xp + 4);
            }
            uint4 pa;
            pa.x = cvtpk(xa.x, xa.y); pa.y = cvtpk(xa.z, xa.w);
            pa.z = cvtpk(xc.x, xc.y); pa.w = cvtpk(xc.z, xc.w);
            *reinterpret_cast<uint4*>(&sA[row][k8]) = pa;
            const float* wp = Wr + (size_t)(o0 + row) * K + k0 + k8;
            float4 wa = *reinterpret_cast<const float4*>(wp);
            float4 wb = *reinterpret_cast<const float4*>(wp + 4);
            uint4 pb;
            pb.x = cvtpk(wa.x, wa.y); pb.y = cvtpk(wa.z, wa.w);
            pb.z = cvtpk(wb.x, wb.y); pb.w = cvtpk(wb.z, wb.w);
            *reinterpret_cast<uint4*>(&sB[row][k8]) = pb;
        }
        __syncthreads();
        #pragma unroll
        for (int kk = 0; kk < 2; ++kk) {
            short8v af[4], bf[4];
            int klo = kk * 32 + (lane >> 4) * 8;
            #pragma unroll
            for (int mm = 0; mm < 4; ++mm)
                af[mm] = *reinterpret_cast<const short8v*>(&sA[wr * 64 + mm * 16 + (lane & 15)][klo]);
            #pragma unroll
            for (int nn = 0; nn < 4; ++nn)
                bf[nn] = *reinterpret_cast<const short8v*>(&sB[wc * 64 + nn * 16 + (lane & 15)][klo]);
            #pragma unroll
            for (int mm = 0; mm < 4; ++mm)
                #pragma unroll
                for (int nn = 0; nn < 4; ++nn)
                    acc[mm][nn] = __builtin_amdgcn_mfma_f32_16x16x32_bf16(af[mm], bf[nn], acc[mm][nn], 0, 0, 0);
        }
        __syncthreads();
    }
    int col0 = o0 + wc * 64;
    int rbase = (lane >> 4) * 4;
    #pragma unroll
    for (int mm = 0; mm < 4; ++mm) {
        #pragma unroll
        for (int j = 0; j < 4; ++j) {
            int gr = n0 + wr * 64 + mm * 16 + rbase + j;
            if (gr >= NN) continue;
            #pragma unroll
            for (int nn = 0; nn < 4; ++nn) {
                int gc = col0 + nn * 16 + (lane & 15);
                size_t idx = (size_t)bz * NN * 256 + (size_t)gr * 256 + gc;
                feat8[idx] = f2fp8(acc[mm][nn][j]);
            }
        }
    }
}

// ---------------- Layer-2 GEMM with fused post2 epilogue (feat2 bf16) ----------------
__global__ __launch_bounds__(256) void gemm2_k(
    const unsigned short* __restrict__ A,   // [NN][256] bf16 (hb)
    const unsigned short* __restrict__ W,   // [256][256] bf16 (Wcat)
    unsigned short* __restrict__ feat2,     // [2][NN][64] bf16
    float* __restrict__ base0, float* __restrict__ base1)
{
    __shared__ unsigned short sA[128][72];
    __shared__ unsigned short sB[128][72];
    const int K = 256;
    int tid = threadIdx.x;
    int wid = tid >> 6, lane = tid & 63;
    int wr = wid >> 1, wc = wid & 1;
    int n0 = blockIdx.x * 128;
    int o0 = blockIdx.y * 128;

    f32x4 acc[4][4] = {};

    for (int k0 = 0; k0 < K; k0 += 64) {
        #pragma unroll
        for (int p = 0; p < 4; ++p) {
            int flat = p * 256 + tid;
            int row = flat >> 3, k8 = (flat & 7) * 8;
            int gr = n0 + row;
            short8v va = {0, 0, 0, 0, 0, 0, 0, 0};
            if (gr < NN) va = *reinterpret_cast<const short8v*>(A + (size_t)gr * K + k0 + k8);
            *reinterpret_cast<short8v*>(&sA[row][k8]) = va;
            short8v vb = *reinterpret_cast<const short8v*>(W + (size_t)(o0 + row) * K + k0 + k8);
            *reinterpret_cast<short8v*>(&sB[row][k8]) = vb;
        }
        __syncthreads();
        #pragma unroll
        for (int kk = 0; kk < 2; ++kk) {
            short8v af[4], bf[4];
            int klo = kk * 32 + (lane >> 4) * 8;
            #pragma unroll
            for (int m = 0; m < 4; ++m)
                af[m] = *reinterpret_cast<const short8v*>(&sA[wr * 64 + m * 16 + (lane & 15)][klo]);
            #pragma unroll
            for (int n = 0; n < 4; ++n)
                bf[n] = *reinterpret_cast<const short8v*>(&sB[wc * 64 + n * 16 + (lane & 15)][klo]);
            #pragma unroll
            for (int m = 0; m < 4; ++m)
                #pragma unroll
                for (int n = 0; n < 4; ++n)
                    acc[m][n] = __builtin_amdgcn_mfma_f32_16x16x32_bf16(af[m], bf[n], acc[m][n], 0, 0, 0);
        }
        __syncthreads();
    }
    int col0 = o0 + wc * 64;
    int sel = col0 >> 6;            // wave-uniform: 0..3
    int rbase = (lane >> 4) * 4;
    #pragma unroll
    for (int m = 0; m < 4; ++m) {
        #pragma unroll
        for (int j = 0; j < 4; ++j) {
            int gr = n0 + wr * 64 + m * 16 + rbase + j;
            if (gr >= NN) continue;
            #pragma unroll
            for (int n = 0; n < 4; ++n) {
                int d = n * 16 + (lane & 15);
                float v = acc[m][n][j];
                size_t o = (size_t)gr * 64 + d;
                if (sel == 0)      feat2[o] = f2bf(v);
                else if (sel == 1) base0[o] = v;
                else if (sel == 2) feat2[(size_t)NN * 64 + o] = f2bf(v);
                else               base1[o] = v;
            }
        }
    }
}

// ---------------- Layer-1 edge softmax + aggregation (H=4, D=64) ----------------
// R19 structure: 1 wave per node (R3/R21 lesson: packing always loses),
// 2-edge ILP, packed f32x2 math, DPP reduce, fp8 gather table.
__global__ __launch_bounds__(64) void agg1_k(
    const unsigned char* __restrict__ feat8,   // [2][NN][256] fp8 e4m3
    const unsigned short* __restrict__ xb,     // [NN][256] bf16 (residual)
    const float* __restrict__ a1,              // [2][256]
    const float* __restrict__ b1,              // [2][256]
    const int* __restrict__ rowptr, const int* __restrict__ csr,
    unsigned short* __restrict__ hb)           // [NN][256] bf16 out
{
    int n = blockIdx.x, lane = threadIdx.x;
    unsigned laneoff = (unsigned)lane * 4u;    // 4 bytes per lane in a 256B row
    int c = lane * 4;
    float4 av0v = *reinterpret_cast<const float4*>(a1 + c);
    float4 av1v = *reinterpret_cast<const float4*>(a1 + 256 + c);
    f32x2 P01[2], P23[2], Q01[2], Q23[2];     // pre-scaled by log2(e)
    P01[0] = f32x2{0.6f * LOG2E * av0v.x, 0.6f * LOG2E * av0v.y};
    P23[0] = f32x2{0.6f * LOG2E * av0v.z, 0.6f * LOG2E * av0v.w};
    Q01[0] = f32x2{0.4f * LOG2E * av0v.x, 0.4f * LOG2E * av0v.y};
    Q23[0] = f32x2{0.4f * LOG2E * av0v.z, 0.4f * LOG2E * av0v.w};
    P01[1] = f32x2{0.6f * LOG2E * av1v.x, 0.6f * LOG2E * av1v.y};
    P23[1] = f32x2{0.6f * LOG2E * av1v.z, 0.6f * LOG2E * av1v.w};
    Q01[1] = f32x2{0.4f * LOG2E * av1v.x, 0.4f * LOG2E * av1v.y};
    Q23[1] = f32x2{0.4f * LOG2E * av1v.z, 0.4f * LOG2E * av1v.w};
    float bsum0 = b1[c + 0] + b1[256 + c + 0];
    float bsum1 = b1[c + 1] + b1[256 + c + 1];
    float bsum2 = b1[c + 2] + b1[256 + c + 2];
    float bsum3 = b1[c + 3] + b1[256 + c + 3];

    f32x2 t01 = {0.f, 0.f}, t23 = {0.f, 0.f};
    #pragma unroll
    for (int r = 0; r < 2; ++r) {
        const char* frB = (const char*)(feat8 + (size_t)r * NN * 256);
        unsigned ud = *reinterpret_cast<const unsigned*>(frB + (((unsigned)n << 8) | laneoff));
        f32x2 fd01 = __builtin_amdgcn_cvt_pk_f32_fp8(ud, false);
        f32x2 fd23 = __builtin_amdgcn_cvt_pk_f32_fp8(ud, true);
        f32x2 Pa = P01[r], Pb = P23[r], Qa = Q01[r], Qb = Q23[r];
        float lsum = 0.f;
        f32x2 a01 = {0.f, 0.f}, a23 = {0.f, 0.f};
        int beg = rowptr[r * (NN + 1) + n], end = rowptr[r * (NN + 1) + n + 1];
        const int* cp = csr + (size_t)r * EE;
        int e = beg;
        for (; e + 2 <= end; e += 2) {
            int s0 = cp[e], s1 = cp[e + 1];
            unsigned u0 = *reinterpret_cast<const unsigned*>(frB + (((unsigned)s0 << 8) | laneoff));
            unsigned u1 = *reinterpret_cast<const unsigned*>(frB + (((unsigned)s1 << 8) | laneoff));
            f32x2 f0a = __builtin_amdgcn_cvt_pk_f32_fp8(u0, false);
            f32x2 f0b = __builtin_amdgcn_cvt_pk_f32_fp8(u0, true);
            f32x2 f1a = __builtin_amdgcn_cvt_pk_f32_fp8(u1, false);
            f32x2 f1b = __builtin_amdgcn_cvt_pk_f32_fp8(u1, true);
            f32x2 t, wv0, wv1;
            t = f0a + fd01; wv0  = Pa * t + Qa * abs2(t);
            t = f0b + fd23; wv0 += Pb * t; wv0 += Qb * abs2(t);
            t = f1a + fd01; wv1  = Pa * t + Qa * abs2(t);
            t = f1b + fd23; wv1 += Pb * t; wv1 += Qb * abs2(t);
            float w0 = wv0.x + wv0.y, w1 = wv1.x + wv1.y;
            ROW16_REDUCE(w0)
            ROW16_REDUCE(w1)
            float p0 = exp2a(w0), p1 = exp2a(w1);
            lsum += p0 + p1;
            f32x2 pb0 = f32x2{p0, p0}, pb1 = f32x2{p1, p1};
            a01 += pb0 * f0a; a23 += pb0 * f0b;
            a01 += pb1 * f1a; a23 += pb1 * f1b;
        }
        if (e < end) {
            int s = cp[e];
            unsigned us = *reinterpret_cast<const unsigned*>(frB + (((unsigned)s << 8) | laneoff));
            f32x2 fa = __builtin_amdgcn_cvt_pk_f32_fp8(us, false);
            f32x2 fb = __builtin_amdgcn_cvt_pk_f32_fp8(us, true);
            f32x2 t, wv;
            t = fa + fd01; wv  = Pa * t + Qa * abs2(t);
            t = fb + fd23; wv += Pb * t; wv += Qb * abs2(t);
            float w = wv.x + wv.y;
            ROW16_REDUCE(w)
            float p = exp2a(w);
            lsum += p;
            f32x2 pbv = f32x2{p, p};
            a01 += pbv * fa; a23 += pbv * fb;
        }
        float inv = 1.f / fmaxf(lsum, 1e-16f);
        f32x2 iv = f32x2{inv, inv};
        t01 += a01 * iv; t23 += a23 * iv;
    }
    unsigned o = ((unsigned)n << 8) + (unsigned)c;
    uint2 xv = *reinterpret_cast<const uint2*>(xb + o);
    float v0 = fmaxf(t01.x + 2.f * bflo(xv.x) + bsum0, 0.f);
    float v1 = fmaxf(t01.y + 2.f * bfhi(xv.x) + bsum1, 0.f);
    float v2 = fmaxf(t23.x + 2.f * bflo(xv.y) + bsum2, 0.f);
    float v3 = fmaxf(t23.y + 2.f * bfhi(xv.y) + bsum3, 0.f);
    ushort4 ho;
    ho.x = f2bf(v0); ho.y = f2bf(v1); ho.z = f2bf(v2); ho.w = f2bf(v3);
    reinterpret_cast<ushort4*>(hb)[((unsigned)n << 6) + (unsigned)lane] = ho;
}

// ---------------- Layer-2 edge softmax + aggregation (H=1, D=64), 4-edge ILP ----------------
__global__ __launch_bounds__(64) void agg2_k(
    const unsigned short* __restrict__ feat2,  // [2][NN][64] bf16
    const float* __restrict__ base0, const float* __restrict__ base1,
    const float* __restrict__ a2,              // [2][64]
    const float* __restrict__ b2,              // [2][64]
    const int* __restrict__ rowptr, const int* __restrict__ csr,
    float* __restrict__ out)
{
    int n = blockIdx.x, lane = threadIdx.x;
    unsigned laneoff = (unsigned)lane * 2u;
    float av0 = a2[lane], av1 = a2[64 + lane];
    float p6a[2] = {0.6f * LOG2E * av0, 0.6f * LOG2E * av1};
    float q4a[2] = {0.4f * LOG2E * av0, 0.4f * LOG2E * av1};
    float bs = b2[lane] + b2[64 + lane];

    float tot = 0.f;
    #pragma unroll
    for (int r = 0; r < 2; ++r) {
        const char* frB = (const char*)(feat2 + (size_t)r * NN * 64);
        float fd = bf2f(*reinterpret_cast<const unsigned short*>(frB + (((unsigned)n << 7) | laneoff)));
        float P = p6a[r], Q = q4a[r];
        float lsum = 0.f, acc = 0.f;
        int beg = rowptr[r * (NN + 1) + n], end = rowptr[r * (NN + 1) + n + 1];
        const int* cp = csr + (size_t)r * EE;
        int e = beg;
        for (; e + 4 <= end; e += 4) {
            int s0 = cp[e], s1 = cp[e + 1], s2 = cp[e + 2], s3 = cp[e + 3];
            float fs0 = bf2f(*reinterpret_cast<const unsigned short*>(frB + (((unsigned)s0 << 7) | laneoff)));
            float fs1 = bf2f(*reinterpret_cast<const unsigned short*>(frB + (((unsigned)s1 << 7) | laneoff)));
            float fs2 = bf2f(*reinterpret_cast<const unsigned short*>(frB + (((unsigned)s2 << 7) | laneoff)));
            float fs3 = bf2f(*reinterpret_cast<const unsigned short*>(frB + (((unsigned)s3 << 7) | laneoff)));
            float ta = fs0 + fd, tb = fs1 + fd, tc = fs2 + fd, td = fs3 + fd;
            float P0 = P * ta + Q * fabsf(ta);
            float P1 = P * tb + Q * fabsf(tb);
            float P2 = P * tc + Q * fabsf(tc);
            float P3 = P * td + Q * fabsf(td);
            ROW16_REDUCE(P0) ROW16_REDUCE(P1) ROW16_REDUCE(P2) ROW16_REDUCE(P3)
            P0 += __shfl_xor(P0, 16); P1 += __shfl_xor(P1, 16); P2 += __shfl_xor(P2, 16); P3 += __shfl_xor(P3, 16);
            P0 += __shfl_xor(P0, 32); P1 += __shfl_xor(P1, 32); P2 += __shfl_xor(P2, 32); P3 += __shfl_xor(P3, 32);
            float p0 = exp2a(P0), p1 = exp2a(P1), p2 = exp2a(P2), p3 = exp2a(P3);
            lsum += (p0 + p1) + (p2 + p3);
            acc += p0 * fs0; acc += p1 * fs1; acc += p2 * fs2; acc += p3 * fs3;
        }
        for (; e < end; ++e) {
            int s = cp[e];
            float fs = bf2f(*reinterpret_cast<const unsigned short*>(frB + (((unsigned)s << 7) | laneoff)));
            float t = fs + fd;
            float w = P * t + Q * fabsf(t);
            ROW16_REDUCE(w)
            w += __shfl_xor(w, 16);
            w += __shfl_xor(w, 32);
            float p = exp2a(w);
            lsum += p;
            acc += p * fs;
        }
        tot += acc / fmaxf(lsum, 1e-16f);
    }
    unsigned o = ((unsigned)n << 6) + (unsigned)lane;
    out[o] = fmaxf(tot + base0[o] + base1[o] + bs, 0.f);
}

extern "C" void kernel_launch(void* const* d_in, const int* in_sizes, int n_in,
                              void* d_out, int out_size, void* d_ws, size_t ws_size,
                              hipStream_t stream) {
    (void)in_sizes; (void)n_in; (void)out_size; (void)ws_size;
    const float* x     = (const float*)d_in[0];
    const int*   src   = (const int*)d_in[1];
    const int*   dst   = (const int*)d_in[2];
    const float* W1    = (const float*)d_in[3];
    const float* a1    = (const float*)d_in[4];
    const float* b1    = (const float*)d_in[5];
    const float* W2    = (const float*)d_in[6];
    const float* a2    = (const float*)d_in[7];
    const float* b2    = (const float*)d_in[8];
    const float* Wres2 = (const float*)d_in[9];
    float* out = (float*)d_out;

    char* w = (char*)d_ws;
    size_t off = 0;
    auto alloc = [&](size_t bytes) -> void* {
        void* p = w + off;
        off = (off + bytes + 255) & ~(size_t)255;
        return p;
    };
    int* cursor = (int*)alloc((size_t)2 * NN * sizeof(int));
    int* rowptr = (int*)alloc((size_t)2 * (NN + 1) * sizeof(int));
    int* csr    = (int*)alloc((size_t)2 * EE * sizeof(int));
    int* rankb  = (int*)alloc((size_t)2 * EE * sizeof(int));
    unsigned char* feat8 = (unsigned char*)alloc((size_t)2 * NN * 256);   // fp8 direct from mega1
    unsigned short* xb = (unsigned short*)alloc((size_t)NN * 256 * 2);
    unsigned short* hb = (unsigned short*)alloc((size_t)NN * 256 * 2);
    unsigned short* Wcatb = (unsigned short*)alloc((size_t)256 * 256 * 2);
    unsigned short* feat2 = (unsigned short*)alloc((size_t)2 * NN * 64 * 2);
    float* base0 = (float*)alloc((size_t)NN * 64 * 4);
    float* base1 = (float*)alloc((size_t)NN * 64 * 4);

    hipMemsetAsync(cursor, 0, (size_t)2 * NN * sizeof(int), stream);

    // mega1: L1 GEMM (fp8 epilogue) + rank atomics + cvt-x + wcat, co-scheduled
    mega1_k<<<MG_GRID, 256, 0, stream>>>(x, W1, feat8, dst, cursor, rankb, xb, W2, Wres2, Wcatb);
    scan_k<<<2, 1024, 0, stream>>>(cursor, rowptr);
    place_k<<<(2 * EE + 255) / 256, 256, 0, stream>>>(src, dst, rankb, rowptr, csr);

    agg1_k<<<NN, 64, 0, stream>>>(feat8, xb, a1, b1, rowptr, csr, hb);

    // Layer 2: GEMM with fused post2 epilogue (bf16 feat2)
    dim3 g2(391, 2, 1);
    gemm2_k<<<g2, 256, 0, stream>>>(hb, Wcatb, feat2, base0, base1);
    agg2_k<<<NN, 64, 0, stream>>>(feat2, base0, base1, a2, b2, rowptr, csr, out);
}

// Round 23
// 369.811 us; speedup vs baseline: 1.1518x; 1.0037x over previous
//
#include <hip/hip_runtime.h>
#include <hip/hip_bf16.h>

#define NN 50000
#define EE 800000

// mega1 block layout: 782 groups of {2 gemm, 1 rank(2048 edges)} = 2346,
// then 3125 cvt-x blocks (1024 float4 each), then 64 wcat blocks (1024 each).
#define MG_INTER 2346
#define MG_CVX0  2346
#define MG_WC0   5471
#define MG_GRID  5535

#define LOG2E 1.4426950408889634f

typedef __attribute__((ext_vector_type(8))) short short8v;
typedef __attribute__((ext_vector_type(4))) float f32x4;
typedef __attribute__((ext_vector_type(2))) float f32x2;

__device__ __forceinline__ float bf2f(unsigned short u) {
    return __uint_as_float(((unsigned int)u) << 16);
}
__device__ __forceinline__ float bflo(unsigned int u) {
    return __uint_as_float(u << 16);
}
__device__ __forceinline__ float bfhi(unsigned int u) {
    return __uint_as_float(u & 0xffff0000u);
}
__device__ __forceinline__ unsigned short f2bf(float f) {
    unsigned int u = __float_as_uint(f);
    unsigned int r = 0x7FFF + ((u >> 16) & 1);
    return (unsigned short)((u + r) >> 16);
}
__device__ __forceinline__ unsigned cvtpk(float lo, float hi) {
    unsigned r;
    asm("v_cvt_pk_bf16_f32 %0, %1, %2" : "=v"(r) : "v"(lo), "v"(hi));
    return r;
}
__device__ __forceinline__ unsigned char f2fp8(float v) {
    int r = __builtin_amdgcn_cvt_pk_fp8_f32(v, v, 0, false);
    return (unsigned char)(r & 0xFF);
}
__device__ __forceinline__ float exp2a(float x) {      // 2^x, single v_exp_f32
    float r;
    asm("v_exp_f32 %0, %1" : "=v"(r) : "v"(x));
    return r;
}
__device__ __forceinline__ f32x2 abs2(f32x2 v) {
    return __builtin_elementwise_abs(v);
}

// DPP butterfly add within a 16-lane row (pure VALU, no LDS pipe).
template<int CTRL>
__device__ __forceinline__ float dppadd(float v) {
    int iv = __float_as_int(v);
    int p = __builtin_amdgcn_update_dpp(0, iv, CTRL, 0xF, 0xF, true);
    return v + __int_as_float(p);
}
#define ROW16_REDUCE(w) \
    w = dppadd<0xB1>(w);  /* quad_perm [1,0,3,2]  : xor1 */ \
    w = dppadd<0x4E>(w);  /* quad_perm [2,3,0,1]  : xor2 */ \
    w = dppadd<0x141>(w); /* ROW_HALF_MIRROR      : quads -> 8 */ \
    w = dppadd<0x140>(w); /* ROW_MIRROR           : 8s -> 16 */

// ---------------- CSR: scan of counts -> rowptr ----------------
__global__ __launch_bounds__(1024) void scan_k(const int* __restrict__ cursor, int* __restrict__ rowptr) {
    int r = blockIdx.x;
    const int* cnt = cursor + (size_t)r * NN;
    int* rp  = rowptr + r * (NN + 1);
    int tid = threadIdx.x;
    const int CH = (NN + 1023) / 1024;   // 49
    int beg = tid * CH;
    int end = beg + CH; if (end > NN) end = NN;
    int s = 0;
    for (int i = beg; i < end && i < NN; ++i) s += cnt[i];
    __shared__ int sums[1024];
    sums[tid] = s;
    __syncthreads();
    for (int offd = 1; offd < 1024; offd <<= 1) {
        int v = 0;
        if (tid >= offd) v = sums[tid - offd];
        __syncthreads();
        sums[tid] += v;
        __syncthreads();
    }
    int run = sums[tid] - s;
    for (int i = beg; i < end && i < NN; ++i) {
        int c = cnt[i];
        rp[i] = run;
        run += c;
    }
    if (tid == 1023) rp[NN] = sums[1023];
}

// place: no atomics — csr[rowptr[dst]+rank] = src
__global__ void place_k(const int* __restrict__ src, const int* __restrict__ dst,
                        const int* __restrict__ rank, const int* __restrict__ rowptr,
                        int* __restrict__ csr) {
    int i = blockIdx.x * 256 + threadIdx.x;
    if (i >= 2 * EE) return;
    int r = (i >= EE) ? 1 : 0;
    int d = dst[i];
    int pos = rowptr[r * (NN + 1) + d] + rank[i];
    csr[r * EE + pos] = src[i];
}

// ---------------- mega1: L1 GEMM (fp32 in, fp8 out direct) + rank + cvt-x + wcat ----------------
// K-chunk 32 staging: LDS 18.4KB (was 36KB) -> 6-8 blocks/CU co-resident, so
// the latency-bound rank-atomic waves get ~1.5-2x more MLP (R18/R22 lesson:
// static LDS gates ALL heterogeneous blocks).
__global__ __launch_bounds__(256) void mega1_k(
    const float* __restrict__ X,       // [NN][256] fp32
    const float* __restrict__ W1,      // [2][256][256] fp32
    unsigned char* __restrict__ feat8, // [2][NN][256] fp8 e4m3 (direct epilogue)
    const int* __restrict__ dst, int* __restrict__ cursor, int* __restrict__ rank,
    unsigned short* __restrict__ xb,   // [NN][256] bf16 out
    const float* __restrict__ W2, const float* __restrict__ Wres2,
    unsigned short* __restrict__ Wcatb)
{
    __shared__ unsigned short sA[128][36];   // 32-k chunk, +4 pad
    __shared__ unsigned short sB[128][36];
    int bid = blockIdx.x;
    int tid = threadIdx.x;

    if (bid >= MG_INTER) {
        if (bid < MG_WC0) {
            // cvt x -> xb: 4 float4 per thread
            int base = (bid - MG_CVX0) * 1024 + tid;     // 3125*1024 = 3,200,000 exactly
            #pragma unroll
            for (int k = 0; k < 4; ++k) {
                int i = base + k * 256;
                float4 v = reinterpret_cast<const float4*>(X)[i];
                uint2 o;
                o.x = cvtpk(v.x, v.y);
                o.y = cvtpk(v.z, v.w);
                reinterpret_cast<uint2*>(xb)[i] = o;
            }
        } else {
            // build Wcat bf16: 4 per thread
            int base = (bid - MG_WC0) * 1024 + tid;      // 64*1024 = 65536 exactly
            #pragma unroll
            for (int k = 0; k < 4; ++k) {
                int i = base + k * 256;
                int o = i >> 8, kk = i & 255;
                int sel = o >> 6, row = o & 63, r = sel >> 1;
                const float* Wsrc = (sel & 1) ? Wres2 : W2;
                Wcatb[i] = f2bf(Wsrc[((size_t)r * 64 + row) * 256 + kk]);
            }
        }
        return;
    }

    int grp = bid / 3, m = bid % 3;
    if (m == 2) {
        // rank block: 2048 edges, 8 pipelined atomics per thread
        int base = grp * 2048 + tid;
        #pragma unroll
        for (int k = 0; k < 8; ++k) {
            int i = base + k * 256;
            if (i < 2 * EE) {
                int r = (i >= EE) ? 1 : 0;
                rank[i] = atomicAdd(&cursor[(size_t)r * NN + dst[i]], 1);
            }
        }
        return;
    }

    // gemm block g : 128x128 tile, K=256, 32-k chunks
    int g = grp * 2 + m;                 // 0..1563
    const int K = 256;
    int bx = g % 391, by = (g / 391) & 1, bz = g / 782;
    int wid = tid >> 6, lane = tid & 63;
    int wr = wid >> 1, wc = wid & 1;
    int n0 = bx * 128;
    int o0 = by * 128;
    const float* Wr = W1 + (size_t)bz * 256 * 256;

    f32x4 acc[4][4] = {};

    for (int k0 = 0; k0 < K; k0 += 32) {
        #pragma unroll
        for (int p = 0; p < 2; ++p) {
            int flat = p * 256 + tid;            // 0..511
            int row = flat >> 2, k8 = (flat & 3) * 8;
            int gr = n0 + row;
            float4 xa = {0.f, 0.f, 0.f, 0.f}, xc = {0.f, 0.f, 0.f, 0.f};
            if (gr < NN) {
                const float* xp = X + (size_t)gr * K + k0 + k8;
                xa = *reinterpret_cast<const float4*>(xp);
                xc = *reinterpret_cast<const float4*>(xp + 4);
            }
            uint4 pa;
            pa.x = cvtpk(xa.x, xa.y); pa.y = cvtpk(xa.z, xa.w);
            pa.z = cvtpk(xc.x, xc.y); pa.w = cvtpk(xc.z, xc.w);
            *reinterpret_cast<uint4*>(&sA[row][k8]) = pa;
            const float* wp = Wr + (size_t)(o0 + row) * K + k0 + k8;
            float4 wa = *reinterpret_cast<const float4*>(wp);
            float4 wb = *reinterpret_cast<const float4*>(wp + 4);
            uint4 pb;
            pb.x = cvtpk(wa.x, wa.y); pb.y = cvtpk(wa.z, wa.w);
            pb.z = cvtpk(wb.x, wb.y); pb.w = cvtpk(wb.z, wb.w);
            *reinterpret_cast<uint4*>(&sB[row][k8]) = pb;
        }
        __syncthreads();
        {
            short8v af[4], bf[4];
            int klo = (lane >> 4) * 8;
            #pragma unroll
            for (int mm = 0; mm < 4; ++mm)
                af[mm] = *reinterpret_cast<const short8v*>(&sA[wr * 64 + mm * 16 + (lane & 15)][klo]);
            #pragma unroll
            for (int nn = 0; nn < 4; ++nn)
                bf[nn] = *reinterpret_cast<const short8v*>(&sB[wc * 64 + nn * 16 + (lane & 15)][klo]);
            #pragma unroll
            for (int mm = 0; mm < 4; ++mm)
                #pragma unroll
                for (int nn = 0; nn < 4; ++nn)
                    acc[mm][nn] = __builtin_amdgcn_mfma_f32_16x16x32_bf16(af[mm], bf[nn], acc[mm][nn], 0, 0, 0);
        }
        __syncthreads();
    }
    int col0 = o0 + wc * 64;
    int rbase = (lane >> 4) * 4;
    #pragma unroll
    for (int mm = 0; mm < 4; ++mm) {
        #pragma unroll
        for (int j = 0; j < 4; ++j) {
            int gr = n0 + wr * 64 + mm * 16 + rbase + j;
            if (gr >= NN) continue;
            #pragma unroll
            for (int nn = 0; nn < 4; ++nn) {
                int gc = col0 + nn * 16 + (lane & 15);
                size_t idx = (size_t)bz * NN * 256 + (size_t)gr * 256 + gc;
                feat8[idx] = f2fp8(acc[mm][nn][j]);
            }
        }
    }
}

// ---------------- Layer-2 GEMM with fused post2 epilogue (feat2 bf16) ----------------
__global__ __launch_bounds__(256) void gemm2_k(
    const unsigned short* __restrict__ A,   // [NN][256] bf16 (hb)
    const unsigned short* __restrict__ W,   // [256][256] bf16 (Wcat)
    unsigned short* __restrict__ feat2,     // [2][NN][64] bf16
    float* __restrict__ base0, float* __restrict__ base1)
{
    __shared__ unsigned short sA[128][72];
    __shared__ unsigned short sB[128][72];
    const int K = 256;
    int tid = threadIdx.x;
    int wid = tid >> 6, lane = tid & 63;
    int wr = wid >> 1, wc = wid & 1;
    int n0 = blockIdx.x * 128;
    int o0 = blockIdx.y * 128;

    f32x4 acc[4][4] = {};

    for (int k0 = 0; k0 < K; k0 += 64) {
        #pragma unroll
        for (int p = 0; p < 4; ++p) {
            int flat = p * 256 + tid;
            int row = flat >> 3, k8 = (flat & 7) * 8;
            int gr = n0 + row;
            short8v va = {0, 0, 0, 0, 0, 0, 0, 0};
            if (gr < NN) va = *reinterpret_cast<const short8v*>(A + (size_t)gr * K + k0 + k8);
            *reinterpret_cast<short8v*>(&sA[row][k8]) = va;
            short8v vb = *reinterpret_cast<const short8v*>(W + (size_t)(o0 + row) * K + k0 + k8);
            *reinterpret_cast<short8v*>(&sB[row][k8]) = vb;
        }
        __syncthreads();
        #pragma unroll
        for (int kk = 0; kk < 2; ++kk) {
            short8v af[4], bf[4];
            int klo = kk * 32 + (lane >> 4) * 8;
            #pragma unroll
            for (int m = 0; m < 4; ++m)
                af[m] = *reinterpret_cast<const short8v*>(&sA[wr * 64 + m * 16 + (lane & 15)][klo]);
            #pragma unroll
            for (int n = 0; n < 4; ++n)
                bf[n] = *reinterpret_cast<const short8v*>(&sB[wc * 64 + n * 16 + (lane & 15)][klo]);
            #pragma unroll
            for (int m = 0; m < 4; ++m)
                #pragma unroll
                for (int n = 0; n < 4; ++n)
                    acc[m][n] = __builtin_amdgcn_mfma_f32_16x16x32_bf16(af[m], bf[n], acc[m][n], 0, 0, 0);
        }
        __syncthreads();
    }
    int col0 = o0 + wc * 64;
    int sel = col0 >> 6;            // wave-uniform: 0..3
    int rbase = (lane >> 4) * 4;
    #pragma unroll
    for (int m = 0; m < 4; ++m) {
        #pragma unroll
        for (int j = 0; j < 4; ++j) {
            int gr = n0 + wr * 64 + m * 16 + rbase + j;
            if (gr >= NN) continue;
            #pragma unroll
            for (int n = 0; n < 4; ++n) {
                int d = n * 16 + (lane & 15);
                float v = acc[m][n][j];
                size_t o = (size_t)gr * 64 + d;
                if (sel == 0)      feat2[o] = f2bf(v);
                else if (sel == 1) base0[o] = v;
                else if (sel == 2) feat2[(size_t)NN * 64 + o] = f2bf(v);
                else               base1[o] = v;
            }
        }
    }
}

// ---------------- Layer-1 edge softmax + aggregation (H=4, D=64) ----------------
__global__ __launch_bounds__(64) void agg1_k(
    const unsigned char* __restrict__ feat8,   // [2][NN][256] fp8 e4m3
    const unsigned short* __restrict__ xb,     // [NN][256] bf16 (residual)
    const float* __restrict__ a1,              // [2][256]
    const float* __restrict__ b1,              // [2][256]
    const int* __restrict__ rowptr, const int* __restrict__ csr,
    unsigned short* __restrict__ hb)           // [NN][256] bf16 out
{
    int n = blockIdx.x, lane = threadIdx.x;
    unsigned laneoff = (unsigned)lane * 4u;    // 4 bytes per lane in a 256B row
    int c = lane * 4;
    float4 av0v = *reinterpret_cast<const float4*>(a1 + c);
    float4 av1v = *reinterpret_cast<const float4*>(a1 + 256 + c);
    f32x2 P01[2], P23[2], Q01[2], Q23[2];     // pre-scaled by log2(e)
    P01[0] = f32x2{0.6f * LOG2E * av0v.x, 0.6f * LOG2E * av0v.y};
    P23[0] = f32x2{0.6f * LOG2E * av0v.z, 0.6f * LOG2E * av0v.w};
    Q01[0] = f32x2{0.4f * LOG2E * av0v.x, 0.4f * LOG2E * av0v.y};
    Q23[0] = f32x2{0.4f * LOG2E * av0v.z, 0.4f * LOG2E * av0v.w};
    P01[1] = f32x2{0.6f * LOG2E * av1v.x, 0.6f * LOG2E * av1v.y};
    P23[1] = f32x2{0.6f * LOG2E * av1v.z, 0.6f * LOG2E * av1v.w};
    Q01[1] = f32x2{0.4f * LOG2E * av1v.x, 0.4f * LOG2E * av1v.y};
    Q23[1] = f32x2{0.4f * LOG2E * av1v.z, 0.4f * LOG2E * av1v.w};
    float bsum0 = b1[c + 0] + b1[256 + c + 0];
    float bsum1 = b1[c + 1] + b1[256 + c + 1];
    float bsum2 = b1[c + 2] + b1[256 + c + 2];
    float bsum3 = b1[c + 3] + b1[256 + c + 3];

    f32x2 t01 = {0.f, 0.f}, t23 = {0.f, 0.f};
    #pragma unroll
    for (int r = 0; r < 2; ++r) {
        const char* frB = (const char*)(feat8 + (size_t)r * NN * 256);
        unsigned ud = *reinterpret_cast<const unsigned*>(frB + (((unsigned)n << 8) | laneoff));
        f32x2 fd01 = __builtin_amdgcn_cvt_pk_f32_fp8(ud, false);
        f32x2 fd23 = __builtin_amdgcn_cvt_pk_f32_fp8(ud, true);
        f32x2 Pa = P01[r], Pb = P23[r], Qa = Q01[r], Qb = Q23[r];
        float lsum = 0.f;
        f32x2 a01 = {0.f, 0.f}, a23 = {0.f, 0.f};
        int beg = rowptr[r * (NN + 1) + n], end = rowptr[r * (NN + 1) + n + 1];
        const int* cp = csr + (size_t)r * EE;
        int e = beg;
        for (; e + 2 <= end; e += 2) {
            int s0 = cp[e], s1 = cp[e + 1];
            unsigned u0 = *reinterpret_cast<const unsigned*>(frB + (((unsigned)s0 << 8) | laneoff));
            unsigned u1 = *reinterpret_cast<const unsigned*>(frB + (((unsigned)s1 << 8) | laneoff));
            f32x2 f0a = __builtin_amdgcn_cvt_pk_f32_fp8(u0, false);
            f32x2 f0b = __builtin_amdgcn_cvt_pk_f32_fp8(u0, true);
            f32x2 f1a = __builtin_amdgcn_cvt_pk_f32_fp8(u1, false);
            f32x2 f1b = __builtin_amdgcn_cvt_pk_f32_fp8(u1, true);
            f32x2 t, wv0, wv1;
            t = f0a + fd01; wv0  = Pa * t + Qa * abs2(t);
            t = f0b + fd23; wv0 += Pb * t; wv0 += Qb * abs2(t);
            t = f1a + fd01; wv1  = Pa * t + Qa * abs2(t);
            t = f1b + fd23; wv1 += Pb * t; wv1 += Qb * abs2(t);
            float w0 = wv0.x + wv0.y, w1 = wv1.x + wv1.y;
            ROW16_REDUCE(w0)
            ROW16_REDUCE(w1)
            float p0 = exp2a(w0), p1 = exp2a(w1);
            lsum += p0 + p1;
            f32x2 pb0 = f32x2{p0, p0}, pb1 = f32x2{p1, p1};
            a01 += pb0 * f0a; a23 += pb0 * f0b;
            a01 += pb1 * f1a; a23 += pb1 * f1b;
        }
        if (e < end) {
            int s = cp[e];
            unsigned us = *reinterpret_cast<const unsigned*>(frB + (((unsigned)s << 8) | laneoff));
            f32x2 fa = __builtin_amdgcn_cvt_pk_f32_fp8(us, false);
            f32x2 fb = __builtin_amdgcn_cvt_pk_f32_fp8(us, true);
            f32x2 t, wv;
            t = fa + fd01; wv  = Pa * t + Qa * abs2(t);
            t = fb + fd23; wv += Pb * t; wv += Qb * abs2(t);
            float w = wv.x + wv.y;
            ROW16_REDUCE(w)
            float p = exp2a(w);
            lsum += p;
            f32x2 pbv = f32x2{p, p};
            a01 += pbv * fa; a23 += pbv * fb;
        }
        float inv = 1.f / fmaxf(lsum, 1e-16f);
        f32x2 iv = f32x2{inv, inv};
        t01 += a01 * iv; t23 += a23 * iv;
    }
    unsigned o = ((unsigned)n << 8) + (unsigned)c;
    uint2 xv = *reinterpret_cast<const uint2*>(xb + o);
    float v0 = fmaxf(t01.x + 2.f * bflo(xv.x) + bsum0, 0.f);
    float v1 = fmaxf(t01.y + 2.f * bfhi(xv.x) + bsum1, 0.f);
    float v2 = fmaxf(t23.x + 2.f * bflo(xv.y) + bsum2, 0.f);
    float v3 = fmaxf(t23.y + 2.f * bfhi(xv.y) + bsum3, 0.f);
    ushort4 ho;
    ho.x = f2bf(v0); ho.y = f2bf(v1); ho.z = f2bf(v2); ho.w = f2bf(v3);
    reinterpret_cast<ushort4*>(hb)[((unsigned)n << 6) + (unsigned)lane] = ho;
}

// ---------------- Layer-2 edge softmax + aggregation (H=1, D=64), 4-edge ILP ----------------
__global__ __launch_bounds__(64) void agg2_k(
    const unsigned short* __restrict__ feat2,  // [2][NN][64] bf16
    const float* __restrict__ base0, const float* __restrict__ base1,
    const float* __restrict__ a2,              // [2][64]
    const float* __restrict__ b2,              // [2][64]
    const int* __restrict__ rowptr, const int* __restrict__ csr,
    float* __restrict__ out)
{
    int n = blockIdx.x, lane = threadIdx.x;
    unsigned laneoff = (unsigned)lane * 2u;
    float av0 = a2[lane], av1 = a2[64 + lane];
    float p6a[2] = {0.6f * LOG2E * av0, 0.6f * LOG2E * av1};
    float q4a[2] = {0.4f * LOG2E * av0, 0.4f * LOG2E * av1};
    float bs = b2[lane] + b2[64 + lane];

    float tot = 0.f;
    #pragma unroll
    for (int r = 0; r < 2; ++r) {
        const char* frB = (const char*)(feat2 + (size_t)r * NN * 64);
        float fd = bf2f(*reinterpret_cast<const unsigned short*>(frB + (((unsigned)n << 7) | laneoff)));
        float P = p6a[r], Q = q4a[r];
        float lsum = 0.f, acc = 0.f;
        int beg = rowptr[r * (NN + 1) + n], end = rowptr[r * (NN + 1) + n + 1];
        const int* cp = csr + (size_t)r * EE;
        int e = beg;
        for (; e + 4 <= end; e += 4) {
            int s0 = cp[e], s1 = cp[e + 1], s2 = cp[e + 2], s3 = cp[e + 3];
            float fs0 = bf2f(*reinterpret_cast<const unsigned short*>(frB + (((unsigned)s0 << 7) | laneoff)));
            float fs1 = bf2f(*reinterpret_cast<const unsigned short*>(frB + (((unsigned)s1 << 7) | laneoff)));
            float fs2 = bf2f(*reinterpret_cast<const unsigned short*>(frB + (((unsigned)s2 << 7) | laneoff)));
            float fs3 = bf2f(*reinterpret_cast<const unsigned short*>(frB + (((unsigned)s3 << 7) | laneoff)));
            float ta = fs0 + fd, tb = fs1 + fd, tc = fs2 + fd, td = fs3 + fd;
            float P0 = P * ta + Q * fabsf(ta);
            float P1 = P * tb + Q * fabsf(tb);
            float P2 = P * tc + Q * fabsf(tc);
            float P3 = P * td + Q * fabsf(td);
            ROW16_REDUCE(P0) ROW16_REDUCE(P1) ROW16_REDUCE(P2) ROW16_REDUCE(P3)
            P0 += __shfl_xor(P0, 16); P1 += __shfl_xor(P1, 16); P2 += __shfl_xor(P2, 16); P3 += __shfl_xor(P3, 16);
            P0 += __shfl_xor(P0, 32); P1 += __shfl_xor(P1, 32); P2 += __shfl_xor(P2, 32); P3 += __shfl_xor(P3, 32);
            float p0 = exp2a(P0), p1 = exp2a(P1), p2 = exp2a(P2), p3 = exp2a(P3);
            lsum += (p0 + p1) + (p2 + p3);
            acc += p0 * fs0; acc += p1 * fs1; acc += p2 * fs2; acc += p3 * fs3;
        }
        for (; e < end; ++e) {
            int s = cp[e];
            float fs = bf2f(*reinterpret_cast<const unsigned short*>(frB + (((unsigned)s << 7) | laneoff)));
            float t = fs + fd;
            float w = P * t + Q * fabsf(t);
            ROW16_REDUCE(w)
            w += __shfl_xor(w, 16);
            w += __shfl_xor(w, 32);
            float p = exp2a(w);
            lsum += p;
            acc += p * fs;
        }
        tot += acc / fmaxf(lsum, 1e-16f);
    }
    unsigned o = ((unsigned)n << 6) + (unsigned)lane;
    out[o] = fmaxf(tot + base0[o] + base1[o] + bs, 0.f);
}

extern "C" void kernel_launch(void* const* d_in, const int* in_sizes, int n_in,
                              void* d_out, int out_size, void* d_ws, size_t ws_size,
                              hipStream_t stream) {
    (void)in_sizes; (void)n_in; (void)out_size; (void)ws_size;
    const float* x     = (const float*)d_in[0];
    const int*   src   = (const int*)d_in[1];
    const int*   dst   = (const int*)d_in[2];
    const float* W1    = (const float*)d_in[3];
    const float* a1    = (const float*)d_in[4];
    const float* b1    = (const float*)d_in[5];
    const float* W2    = (const float*)d_in[6];
    const float* a2    = (const float*)d_in[7];
    const float* b2    = (const float*)d_in[8];
    const float* Wres2 = (const float*)d_in[9];
    float* out = (float*)d_out;

    char* w = (char*)d_ws;
    size_t off = 0;
    auto alloc = [&](size_t bytes) -> void* {
        void* p = w + off;
        off = (off + bytes + 255) & ~(size_t)255;
        return p;
    };
    int* cursor = (int*)alloc((size_t)2 * NN * sizeof(int));
    int* rowptr = (int*)alloc((size_t)2 * (NN + 1) * sizeof(int));
    int* csr    = (int*)alloc((size_t)2 * EE * sizeof(int));
    int* rankb  = (int*)alloc((size_t)2 * EE * sizeof(int));
    unsigned char* feat8 = (unsigned char*)alloc((size_t)2 * NN * 256);   // fp8 direct from mega1
    unsigned short* xb = (unsigned short*)alloc((size_t)NN * 256 * 2);
    unsigned short* hb = (unsigned short*)alloc((size_t)NN * 256 * 2);
    unsigned short* Wcatb = (unsigned short*)alloc((size_t)256 * 256 * 2);
    unsigned short* feat2 = (unsigned short*)alloc((size_t)2 * NN * 64 * 2);
    float* base0 = (float*)alloc((size_t)NN * 64 * 4);
    float* base1 = (float*)alloc((size_t)NN * 64 * 4);

    hipMemsetAsync(cursor, 0, (size_t)2 * NN * sizeof(int), stream);

    // mega1: L1 GEMM (fp8 epilogue) + rank atomics + cvt-x + wcat, co-scheduled
    mega1_k<<<MG_GRID, 256, 0, stream>>>(x, W1, feat8, dst, cursor, rankb, xb, W2, Wres2, Wcatb);
    scan_k<<<2, 1024, 0, stream>>>(cursor, rowptr);
    place_k<<<(2 * EE + 255) / 256, 256, 0, stream>>>(src, dst, rankb, rowptr, csr);

    agg1_k<<<NN, 64, 0, stream>>>(feat8, xb, a1, b1, rowptr, csr, hb);

    // Layer 2: GEMM with fused post2 epilogue (bf16 feat2)
    dim3 g2(391, 2, 1);
    gemm2_k<<<g2, 256, 0, stream>>>(hb, Wcatb, feat2, base0, base1);
    agg2_k<<<NN, 64, 0, stream>>>(feat2, base0, base1, a2, b2, rowptr, csr, out);
}